// Round 10
// baseline (69.927 us; speedup 1.0000x reference)
//
#include <hip/hip_runtime.h>
#include <hip/hip_bf16.h>
#include <math.h>

#define N_ROWS 8192
#define N_HALF 4096
#define D 128
#define TILES 64                 // 8192 / 128
// scale = sqrt(2 * log2(e)): zb_i . zb_j = 2*log2(e)*cos -> exp2(dot) = exp(2*cos)
#define ZSCALE 1.6986437717f
#define LN2 0.69314718056f

typedef __attribute__((ext_vector_type(8))) short bfrag;   // 8 bf16 = 4 VGPR
typedef __attribute__((ext_vector_type(4))) float f32x4;

__device__ __forceinline__ float fast_exp2(float x) {
#if __has_builtin(__builtin_amdgcn_exp2f)
    return __builtin_amdgcn_exp2f(x);
#else
    return exp2f(x);
#endif
}

// ---------------- kernel 1: normalize rows -> scaled bf16 z; zero denom ----------------
__global__ __launch_bounds__(256) void normalize_kernel(
    const float* __restrict__ p1, const float* __restrict__ p2,
    ushort* __restrict__ zb, float* __restrict__ denom)
{
    if (blockIdx.x < 32) denom[blockIdx.x * 256 + threadIdx.x] = 0.0f;  // re-zero every launch
    const int row = blockIdx.x * 4 + (threadIdx.x >> 6);
    const int lane = threadIdx.x & 63;
    const float* src = (row < N_HALF) ? (p1 + (size_t)row * D)
                                      : (p2 + (size_t)(row - N_HALF) * D);
    float2 v = ((const float2*)src)[lane];
    float ss = v.x * v.x + v.y * v.y;
    #pragma unroll
    for (int m = 1; m < 64; m <<= 1) ss += __shfl_xor(ss, m);
    float inv = ZSCALE / fmaxf(sqrtf(ss), 1e-12f);
    __hip_bfloat16 h0 = __float2bfloat16(v.x * inv);
    __hip_bfloat16 h1 = __float2bfloat16(v.y * inv);
    ushort2 u; u.x = *(ushort*)&h0; u.y = *(ushort*)&h1;
    ((ushort2*)(zb + (size_t)row * D))[lane] = u;
}

// ---------------- kernel 2: upper-triangle tile-pair MFMA + exp2, dual credit ----------------
// Block (ti,tj), ti<=tj: compute 128x128 tile of exp(sim); credit row-sums to
// i-rows (row path) and, for ti<tj, to j-rows (col path, symmetry).
// B staged per 64-col half via wave-private global_load_lds + counted vmcnt (no
// main-loop barriers). LDS slot s (16B): col r=s>>4, k-chunk c16=(s&15)^(r&7).
__global__ __launch_bounds__(256, 2) void simloss_tri(
    const ushort* __restrict__ zb, float* __restrict__ denom,
    float* __restrict__ posv)
{
    const int ti = blockIdx.x & (TILES - 1);
    const int tj = blockIdx.x >> 6;
    if (tj < ti) return;                     // lower triangle: exit
    __shared__ ushort Bs[2][64 * 128];       // 2 x 16 KB
    __shared__ float red[128][4];
    const int t = threadIdx.x;
    const int w = t >> 6;                    // wave 0..3 -> 16-col slice per half
    const int l = t & 63;
    const int l15 = l & 15, lh = l >> 4;
    const int iBase = ti * 128;
    const int jBase = tj * 128;
    const bool diag = (ti == tj);
    const bool posT = (tj == ti + 32) && (ti < 32);   // partner tile

#define STAGE(buf, jB)                                                          \
    {                                                                           \
        _Pragma("unroll")                                                       \
        for (int i = 0; i < 4; ++i) {                                           \
            const int s = w * 256 + i * 64 + l;                                 \
            const int r = s >> 4;                                               \
            const int c = (s & 15) ^ (r & 7);                                   \
            const ushort* g = zb + (size_t)((jB) + r) * D + c * 8;              \
            ushort* lp = (buf) + (size_t)s * 8;                                 \
            __builtin_amdgcn_global_load_lds(                                   \
                (const __attribute__((address_space(1))) unsigned int*)g,       \
                (__attribute__((address_space(3))) unsigned int*)lp, 16, 0, 0); \
        }                                                                       \
    }

    STAGE(&Bs[0][0], jBase);                 // half 0 in flight

    // A tile (128 rows x 128 k) in registers
    bfrag a[8][4];
    #pragma unroll
    for (int m = 0; m < 8; ++m) {
        const ushort* rp = zb + (size_t)(iBase + m * 16 + l15) * D;
        #pragma unroll
        for (int ks = 0; ks < 4; ++ks)
            a[m][ks] = *(const bfrag*)(rp + ks * 32 + lh * 8);
    }

    float rs[8][4];
    #pragma unroll
    for (int m = 0; m < 8; ++m)
        #pragma unroll
        for (int r = 0; r < 4; ++r) rs[m][r] = 0.0f;
    float cs0 = 0.0f, cs1 = 0.0f;            // per-lane col sums (half 0 / 1)

    const int cB = w * 16 + l15;             // col within a half

    #pragma unroll 1
    for (int h = 0; h < 2; ++h) {
        const ushort* bufc = &Bs[h][0];
        if (h == 0) {
            STAGE(&Bs[1][0], jBase + 64);    // half 1 in flight
            asm volatile("s_waitcnt vmcnt(4)" ::: "memory");   // half 0 landed
        } else {
            asm volatile("s_waitcnt vmcnt(0)" ::: "memory");
        }

        bfrag b[4];
        #pragma unroll
        for (int ks = 0; ks < 4; ++ks) {
            const int k16 = ks * 4 + lh;
            const int slot = cB * 16 + (k16 ^ (cB & 7));
            b[ks] = *(const bfrag*)(bufc + slot * 8);
        }

        f32x4 c[8];
        #pragma unroll
        for (int m = 0; m < 8; ++m) { f32x4 z4 = {0.f, 0.f, 0.f, 0.f}; c[m] = z4; }
        #pragma unroll
        for (int ks = 0; ks < 4; ++ks)
            #pragma unroll
            for (int m = 0; m < 8; ++m)
                c[m] = __builtin_amdgcn_mfma_f32_16x16x32_bf16(a[m][ks], b[ks], c[m], 0, 0, 0);

        const int colTile = h * 64 + cB;     // col within the 128-col tile
        if (diag) {                          // diag tile: row path only, zero self
            #pragma unroll
            for (int m = 0; m < 8; ++m)
                #pragma unroll
                for (int r = 0; r < 4; ++r) {
                    const int rowLocal = m * 16 + lh * 4 + r;
                    float e = fast_exp2(c[m][r]);
                    rs[m][r] += (rowLocal == colTile) ? 0.0f : e;
                }
        } else {                             // off-diag: row + col credit
            float csh = 0.0f;
            #pragma unroll
            for (int m = 0; m < 8; ++m)
                #pragma unroll
                for (int r = 0; r < 4; ++r) {
                    float e = fast_exp2(c[m][r]);
                    rs[m][r] += e;
                    csh += e;
                }
            if (h == 0) cs0 += csh; else cs1 += csh;
        }
        if (posT && (l15 >> 2) == lh) {      // partner diagonal element
            const int m = h * 4 + w;
            const float val = c[m][l15 & 3] * LN2;   // = 2*cos
            const int rowLocal = m * 16 + lh * 4 + (l15 & 3);  // == colTile
            posv[iBase + rowLocal] = val;
            posv[jBase + rowLocal] = val;    // jBase = iBase + 4096
        }
    }
#undef STAGE

    // col path: reduce over the 4 lanes sharing a column (xor 16, 32)
    if (!diag) {
        cs0 += __shfl_xor(cs0, 16); cs0 += __shfl_xor(cs0, 32);
        cs1 += __shfl_xor(cs1, 16); cs1 += __shfl_xor(cs1, 32);
        if (lh == 0) {
            atomicAdd(&denom[jBase + cB], cs0);
            atomicAdd(&denom[jBase + 64 + cB], cs1);
        }
    }

    // row path: reduce rs over the 16 cols held across l15 lanes
    #pragma unroll
    for (int m = 0; m < 8; ++m)
        #pragma unroll
        for (int r = 0; r < 4; ++r) {
            float v = rs[m][r];
            v += __shfl_xor(v, 1); v += __shfl_xor(v, 2);
            v += __shfl_xor(v, 4); v += __shfl_xor(v, 8);
            rs[m][r] = v;
        }
    if (l15 == 0) {
        #pragma unroll
        for (int m = 0; m < 8; ++m)
            #pragma unroll
            for (int r = 0; r < 4; ++r)
                red[m * 16 + lh * 4 + r][w] = rs[m][r];
    }
    __syncthreads();
    if (t < 128) {
        float v = red[t][0] + red[t][1] + red[t][2] + red[t][3];
        atomicAdd(&denom[iBase + t], v);
    }
}

// ---------------- kernel 3: per-row loss + per-block deterministic sum ----------------
__global__ __launch_bounds__(256) void rowloss_kernel(
    const float* __restrict__ denom, const float* __restrict__ posv,
    float* __restrict__ bsum)
{
    const int row = blockIdx.x * 256 + threadIdx.x;
    float loss = logf(denom[row]) - posv[row];
    #pragma unroll
    for (int m = 1; m < 64; m <<= 1) loss += __shfl_xor(loss, m);
    __shared__ float red[4];
    if ((threadIdx.x & 63) == 0) red[threadIdx.x >> 6] = loss;
    __syncthreads();
    if (threadIdx.x == 0) bsum[blockIdx.x] = red[0] + red[1] + red[2] + red[3];
}

// ---------------- kernel 4: final reduce of 32 block sums ----------------
__global__ __launch_bounds__(64) void final_reduce(
    const float* __restrict__ bsum, float* __restrict__ out)
{
    const int t = threadIdx.x;
    float s = (t < 32) ? bsum[t] : 0.0f;
    #pragma unroll
    for (int m = 1; m < 64; m <<= 1) s += __shfl_xor(s, m);
    if (t == 0) out[0] = s * (1.0f / (float)N_ROWS);
}

extern "C" void kernel_launch(void* const* d_in, const int* in_sizes, int n_in,
                              void* d_out, int out_size, void* d_ws, size_t ws_size,
                              hipStream_t stream) {
    const float* proj1 = (const float*)d_in[0];
    const float* proj2 = (const float*)d_in[1];
    float* out = (float*)d_out;

    char* ws = (char*)d_ws;
    ushort* zb    = (ushort*)ws;                                    // 2 MB
    float*  denom = (float*)(ws + (size_t)2 * 1024 * 1024);         // 32 KB
    float*  posv  = (float*)(ws + (size_t)2 * 1024 * 1024 + 256 * 1024);  // 32 KB
    float*  bsum  = (float*)(ws + (size_t)2 * 1024 * 1024 + 512 * 1024);  // 128 B

    normalize_kernel<<<N_ROWS / 4, 256, 0, stream>>>(proj1, proj2, zb, denom);
    simloss_tri<<<TILES * TILES, 256, 0, stream>>>(zb, denom, posv);
    rowloss_kernel<<<N_ROWS / 256, 256, 0, stream>>>(denom, posv, bsum);
    final_reduce<<<1, 64, 0, stream>>>(bsum, out);
}

// Round 11
// 32.363 us; speedup vs baseline: 2.1607x; 2.1607x over previous
//
#include <hip/hip_runtime.h>
#include <hip/hip_bf16.h>
#include <math.h>

#define N_ROWS 8192
#define N_HALF 4096
#define D 128
#define SEGS 8
#define IBLKS (N_ROWS / 128)            // 64 i-tiles of 128 rows
#define SEGCOLS (N_ROWS / SEGS)         // 1024 cols per block
#define HALVES (SEGCOLS / 64)           // 16 halves of 64 cols
// scale = sqrt(2 * log2(e)): zq_i . zq_j = 2*log2(e)*cos -> exp2(dot) = exp(2*cos)
#define ZSCALE 1.6986437717f
#define LN2 0.69314718056f

typedef __attribute__((ext_vector_type(8))) int   i32x8;   // 32B fp8 fragment
typedef __attribute__((ext_vector_type(4))) int   i32x4;
typedef __attribute__((ext_vector_type(4))) float f32x4;

__device__ __forceinline__ float fast_exp2(float x) {
#if __has_builtin(__builtin_amdgcn_exp2f)
    return __builtin_amdgcn_exp2f(x);
#else
    return exp2f(x);
#endif
}

// ---------------- kernel 1: normalize rows; emit scaled fp8 e4m3 z ----------------
__global__ __launch_bounds__(256) void normalize_kernel(
    const float* __restrict__ p1, const float* __restrict__ p2,
    unsigned char* __restrict__ zq)
{
    const int row = blockIdx.x * 4 + (threadIdx.x >> 6);
    const int lane = threadIdx.x & 63;
    const float* src = (row < N_HALF) ? (p1 + (size_t)row * D)
                                      : (p2 + (size_t)(row - N_HALF) * D);
    float2 v = ((const float2*)src)[lane];
    float ss = v.x * v.x + v.y * v.y;
    #pragma unroll
    for (int m = 1; m < 64; m <<= 1) ss += __shfl_xor(ss, m);
    float inv = ZSCALE / fmaxf(sqrtf(ss), 1e-12f);
    // pack 2 fp8 (RNE, OCP e4m3): byte0 = k=2*lane, byte1 = k=2*lane+1
    int pk = __builtin_amdgcn_cvt_pk_fp8_f32(v.x * inv, v.y * inv, 0, false);
    ((ushort*)(zq + (size_t)row * D))[lane] = (ushort)(pk & 0xFFFF);
}

// ---------------- kernel 2: barrier-free dbuf DMA + MX-fp8 K=128 MFMA Gram ----------------
// Wave-private staging/reads as R9. Half-buffer = 64 cols x 128 B = 512 slots of
// 16B. Slot s: col r = s>>3, chunk c16 = (s&7)^(r&7) (swizzle pair, rule #21).
// Read (col cB, quarter lh): 32B = chunks {2lh, 2lh+1}.
__global__ __launch_bounds__(256, 2) void simloss_mfma(
    const unsigned char* __restrict__ zq, float* __restrict__ partial,
    float* __restrict__ posv)
{
    __shared__ unsigned char Bs[2][64 * 128];   // 2 x 8 KB
    __shared__ float red[128][4];
    const int t = threadIdx.x;
    const int w = t >> 6;                // wave 0..3 -> 16-col slice of each half
    const int l = t & 63;
    const int l15 = l & 15, lh = l >> 4;
    const int bi = blockIdx.x & (IBLKS - 1);
    const int seg = blockIdx.x >> 6;
    const int iBase = bi * 128;
    const int segBase = seg * SEGCOLS;
    const int pBase = iBase ^ N_HALF;    // partner tile base (128-aligned)

// stage this wave's 16-col slice of one 64x128B half: 2 DMA issues.
#define STAGE(buf, jB)                                                          \
    {                                                                           \
        _Pragma("unroll")                                                       \
        for (int i = 0; i < 2; ++i) {                                           \
            const int s = w * 128 + i * 64 + l;                                 \
            const int r = s >> 3;                                               \
            const int c = (s & 7) ^ (r & 7);                                    \
            const unsigned char* g = zq + (size_t)((jB) + r) * D + c * 16;      \
            unsigned char* lp = (buf) + (size_t)s * 16;                         \
            __builtin_amdgcn_global_load_lds(                                   \
                (const __attribute__((address_space(1))) unsigned int*)g,       \
                (__attribute__((address_space(3))) unsigned int*)lp, 16, 0, 0); \
        }                                                                       \
    }

    STAGE(&Bs[0][0], segBase);           // prologue: half 0 in flight

    // A tile (128 rows x 128 k fp8) in registers: 8 m-tiles x 32 B
    i32x8 a[8];
    #pragma unroll
    for (int m = 0; m < 8; ++m)
        a[m] = *(const i32x8*)(zq + (size_t)(iBase + m * 16 + l15) * D + lh * 32);

    float rs[8][4];
    #pragma unroll
    for (int m = 0; m < 8; ++m)
        #pragma unroll
        for (int r = 0; r < 4; ++r) rs[m][r] = 0.0f;

    const int cB = w * 16 + l15;         // this lane's col within each half
    const int slot0base = cB * 8;

    #pragma unroll 1
    for (int h = 0; h < HALVES; ++h) {
        const int jBase = segBase + h * 64;
        const unsigned char* bufc = &Bs[h & 1][0];

        if (h + 1 < HALVES) {
            STAGE(&Bs[(h + 1) & 1][0], jBase + 64);          // next half in flight
            asm volatile("s_waitcnt vmcnt(2)" ::: "memory"); // current half landed
        } else {
            asm volatile("s_waitcnt vmcnt(0)" ::: "memory");
        }

        const int slot0 = slot0base + ((2 * lh)     ^ (cB & 7));
        const int slot1 = slot0base + ((2 * lh + 1) ^ (cB & 7));
        i32x4 blo = *(const i32x4*)(bufc + slot0 * 16);
        i32x4 bhi = *(const i32x4*)(bufc + slot1 * 16);
        i32x8 bv;
        bv[0] = blo[0]; bv[1] = blo[1]; bv[2] = blo[2]; bv[3] = blo[3];
        bv[4] = bhi[0]; bv[5] = bhi[1]; bv[6] = bhi[2]; bv[7] = bhi[3];

        f32x4 c[8];
        #pragma unroll
        for (int m = 0; m < 8; ++m) { f32x4 z4 = {0.f, 0.f, 0.f, 0.f}; c[m] = z4; }
        #pragma unroll
        for (int m = 0; m < 8; ++m)
            c[m] = __builtin_amdgcn_mfma_scale_f32_16x16x128_f8f6f4(
                       a[m], bv, c[m], 0, 0,           // cbsz=FP8, blgp=FP8
                       0, 0x7F7F7F7Fu,                 // scale A = 2^0
                       0, 0x7F7F7F7Fu);                // scale B = 2^0

        if ((jBase & ~127) == iBase) {   // rare: half covers self-diagonal
            const int sOff = jBase - iBase;          // 0 or 64
            #pragma unroll
            for (int m = 0; m < 8; ++m)
                #pragma unroll
                for (int r = 0; r < 4; ++r) {
                    const int rowLocal = m * 16 + lh * 4 + r;
                    float e = fast_exp2(c[m][r]);
                    rs[m][r] += (rowLocal == sOff + cB) ? 0.0f : e;
                }
        } else {                         // hot path
            #pragma unroll
            for (int m = 0; m < 8; ++m)
                #pragma unroll
                for (int r = 0; r < 4; ++r)
                    rs[m][r] += fast_exp2(c[m][r]);
        }
        if ((jBase & ~127) == pBase) {   // rare: half covers partner diagonal
            const int pOff = jBase - pBase;          // 0 or 64
            #pragma unroll
            for (int m = 0; m < 8; ++m)
                #pragma unroll
                for (int r = 0; r < 4; ++r) {
                    const int rowLocal = m * 16 + lh * 4 + r;
                    if (rowLocal == pOff + cB)
                        posv[iBase + rowLocal] = c[m][r] * LN2;   // = 2*cos
                }
        }
    }
#undef STAGE

    // reduce rs over the 16 cols held across l15 lanes
    #pragma unroll
    for (int m = 0; m < 8; ++m)
        #pragma unroll
        for (int r = 0; r < 4; ++r) {
            float v = rs[m][r];
            v += __shfl_xor(v, 1); v += __shfl_xor(v, 2);
            v += __shfl_xor(v, 4); v += __shfl_xor(v, 8);
            rs[m][r] = v;
        }
    if (l15 == 0) {
        #pragma unroll
        for (int m = 0; m < 8; ++m)
            #pragma unroll
            for (int r = 0; r < 4; ++r)
                red[m * 16 + lh * 4 + r][w] = rs[m][r];
    }
    __syncthreads();                     // real cross-wave reduce: keep
    if (t < 128) {
        float v = red[t][0] + red[t][1] + red[t][2] + red[t][3];
        partial[(size_t)seg * N_ROWS + iBase + t] = v;
    }
}

// ---------------- kernel 3: per-row loss + per-block deterministic sum ----------------
__global__ __launch_bounds__(256) void rowloss_kernel(
    const float* __restrict__ partial, const float* __restrict__ posv,
    float* __restrict__ bsum)
{
    const int row = blockIdx.x * 256 + threadIdx.x;
    float denom = 0.0f;
    #pragma unroll
    for (int s = 0; s < SEGS; ++s) denom += partial[(size_t)s * N_ROWS + row];
    float loss = logf(denom) - posv[row];
    #pragma unroll
    for (int m = 1; m < 64; m <<= 1) loss += __shfl_xor(loss, m);
    __shared__ float red[4];
    if ((threadIdx.x & 63) == 0) red[threadIdx.x >> 6] = loss;
    __syncthreads();
    if (threadIdx.x == 0) bsum[blockIdx.x] = red[0] + red[1] + red[2] + red[3];
}

// ---------------- kernel 4: final reduce of 32 block sums ----------------
__global__ __launch_bounds__(64) void final_reduce(
    const float* __restrict__ bsum, float* __restrict__ out)
{
    const int t = threadIdx.x;
    float s = (t < 32) ? bsum[t] : 0.0f;
    #pragma unroll
    for (int m = 1; m < 64; m <<= 1) s += __shfl_xor(s, m);
    if (t == 0) out[0] = s * (1.0f / (float)N_ROWS);
}

extern "C" void kernel_launch(void* const* d_in, const int* in_sizes, int n_in,
                              void* d_out, int out_size, void* d_ws, size_t ws_size,
                              hipStream_t stream) {
    const float* proj1 = (const float*)d_in[0];
    const float* proj2 = (const float*)d_in[1];
    float* out = (float*)d_out;

    char* ws = (char*)d_ws;
    unsigned char* zq = (unsigned char*)ws;                          // 1 MB
    float* partial = (float*)(ws + (size_t)1 * 1024 * 1024);         // 256 KB
    float* posv    = (float*)(ws + (size_t)1536 * 1024);             // 32 KB
    float* bsum    = (float*)(ws + (size_t)1792 * 1024);             // 128 B

    normalize_kernel<<<N_ROWS / 4, 256, 0, stream>>>(proj1, proj2, zq);
    simloss_mfma<<<IBLKS * SEGS, 256, 0, stream>>>(zq, partial, posv);
    rowloss_kernel<<<N_ROWS / 256, 256, 0, stream>>>(partial, posv, bsum);
    final_reduce<<<1, 64, 0, stream>>>(bsum, out);
}